// Round 12
// baseline (60.569 us; speedup 1.0000x reference)
//
#include <hip/hip_runtime.h>
#include <hip/hip_bf16.h>
#include <math.h>

// Problem constants
#define BB   2
#define LL   2048
#define DD   512
#define KK   32
#define BL   (BB*LL)      // 4096
#define NCH  64           // chunks along L

typedef unsigned short ushort_t;
typedef __bf16 bf16x8 __attribute__((ext_vector_type(8)));
typedef float  f32x4  __attribute__((ext_vector_type(4)));
typedef unsigned short ushort8 __attribute__((ext_vector_type(8)));

__device__ __forceinline__ void gl_lds16(const void* g, void* l) {
    __builtin_amdgcn_global_load_lds(
        (const __attribute__((address_space(1))) void*)g,
        (__attribute__((address_space(3))) void*)l, 16, 0, 0);
}
__device__ __forceinline__ ushort_t f2b(float f) {
    __bf16 b = (__bf16)f; return *(ushort_t*)&b;
}
__device__ __forceinline__ float b2f(ushort_t u) {
    unsigned int x = ((unsigned int)u) << 16; return *(float*)&x;
}

// ---------------------------------------------------------------------------
// prep: z=0: W1^T->Wct[0:512]; z=1: Wv^T->Wct[512:]; z=2: (g.Wo)^T->Wot;
//       z=3: Upart/Vpart[kg][n] partial GEMV (no atomics);
//       z=4: W2^T -> W2T bf16 [32][512]
// (x->bf16 cast is gone: gemm1 stages A directly from f32 x via gl_lds)
// ---------------------------------------------------------------------------
__global__ __launch_bounds__(256) void prep(const float* __restrict__ W1,
                                            const float* __restrict__ Wv,
                                            const float* __restrict__ Wo,
                                            const float* __restrict__ W2,
                                            const float* __restrict__ lng,
                                            const float* __restrict__ lnb,
                                            const float* __restrict__ bo,
                                            __hip_bfloat16* __restrict__ Wct,
                                            __hip_bfloat16* __restrict__ Wot,
                                            __hip_bfloat16* __restrict__ W2T,
                                            float* __restrict__ Upart,
                                            float* __restrict__ Vpart)
{
    __shared__ float tile[32][33];
    const int bz = blockIdx.z;
    const int tx = threadIdx.x, ty = threadIdx.y;
    const int t = ty * 32 + tx;

    if (bz == 3) {                      // Upart/Vpart: 16 k-panel blocks
        if (blockIdx.x != 0) return;
        const int kg = blockIdx.y;      // 0..15
        const int k0 = kg * 32;
        float u0 = 0.f, u1 = 0.f, v0 = 0.f, v1 = 0.f;
        #pragma unroll 4
        for (int k = 0; k < 32; ++k) {
            const float g1 = lng[k0 + k], b1v = lnb[k0 + k];
            const float w0 = Wo[(size_t)(k0 + k) * 512 + t];
            const float w1 = Wo[(size_t)(k0 + k) * 512 + t + 256];
            u0 = fmaf(g1, w0, u0);  u1 = fmaf(g1, w1, u1);
            v0 = fmaf(b1v, w0, v0); v1 = fmaf(b1v, w1, v1);
        }
        if (kg == 0) { v0 += bo[t]; v1 += bo[t + 256]; }
        Upart[kg * 512 + t] = u0;       Upart[kg * 512 + t + 256] = u1;
        Vpart[kg * 512 + t] = v0;       Vpart[kg * 512 + t + 256] = v1;
        return;
    }
    if (bz == 4) {                      // W2 [512][32] -> W2T bf16 [32][512]
        if (blockIdx.x != 0) return;
        const int r0 = blockIdx.y * 32;       // d-rows
        #pragma unroll
        for (int i = 0; i < 4; ++i)
            tile[ty + 8 * i][tx] = W2[(size_t)(r0 + ty + 8 * i) * 32 + tx];
        __syncthreads();
        #pragma unroll
        for (int i = 0; i < 4; ++i)
            W2T[(size_t)(ty + 8 * i) * 512 + r0 + tx] =
                __float2bfloat16(tile[tx][ty + 8 * i]);
        return;
    }
    // transpose planes 0..2
    const float* src = bz == 0 ? W1 : (bz == 1 ? Wv : Wo);
    __hip_bfloat16* dst = bz == 0 ? Wct
                        : (bz == 1 ? Wct + 512 * 512 : Wot);
    const int r0 = blockIdx.y * 32, c0 = blockIdx.x * 32;
    #pragma unroll
    for (int i = 0; i < 4; ++i)
        tile[ty + 8 * i][tx] = src[(size_t)(r0 + ty + 8 * i) * 512 + c0 + tx];
    __syncthreads();
    const float sc = (bz == 2) ? lng[r0 + tx] : 1.f;
    #pragma unroll
    for (int i = 0; i < 4; ++i)
        dst[(size_t)(c0 + ty + 8 * i) * 512 + r0 + tx] =
            __float2bfloat16(tile[tx][ty + 8 * i] * sc);
}

// ---------------------------------------------------------------------------
// bf16 MFMA GEMM: C[M,N] = A[M,512] @ Bt[N,512]^T, BM x 128 tile, 4 waves.
// MODE 0: A staged DIRECTLY from f32 Af via global_load_lds (f32 LDS tile,
//         16B-unit XOR swizzle on global source + same XOR on ds_read,
//         cvt->bf16 in the fragment load). Fuses the x->bf16 cast.
//         cols<512 -> outH = bf16(tanh(.+b0)); cols>=512 -> outV = bf16(.+b1)
// MODE 1: A bf16 via global_load_lds. Fused-LN epilogue:
//         out = resid + rs*. - rs*mu*U[col] + VBc[col]
// ---------------------------------------------------------------------------
template<int BM, int MODE>
__global__ __launch_bounds__(256) void gemm_mfma(
    const ushort_t* __restrict__ A, const float* __restrict__ Af,
    const ushort_t* __restrict__ Bt,
    const float* __restrict__ bias0, const float* __restrict__ bias1,
    const float* __restrict__ resid,
    __hip_bfloat16* __restrict__ outH, __hip_bfloat16* __restrict__ outV,
    float* __restrict__ outF, const float* __restrict__ stats)
{
    constexpr int WROWS = BM / 2;
    constexpr int MF    = WROWS / 16;
    constexpr int ACH   = BM / 32;      // MODE 1: bf16 A pieces/thread
    constexpr int APF   = BM / 16;      // MODE 0: f32 A 16B-pieces/thread
    __shared__ __align__(16) ushort_t As[MODE == 0 ? BM * 128 : BM * 64];
    __shared__ __align__(16) ushort_t Bs[128 * 64];
    __shared__ float muL[BM], rsL[BM], uL[128], vbL[128];

    const int t  = threadIdx.x;
    const int m0 = blockIdx.y * BM, n0 = blockIdx.x * 128;
    const int l  = t & 63, w = t >> 6;
    const int wr = w >> 1, wc = w & 1;
    const int l15 = l & 15, hi = l >> 4;

    if (MODE == 1) {
        if (t < BM) {
            float4 st = *(const float4*)(stats + (size_t)(m0 + t) * 4);
            float s = st.x + st.z, s2 = st.y + st.w;
            float mu = s * (1.f / 512), var = s2 * (1.f / 512) - mu * mu;
            muL[t] = mu;
            rsL[t] = rsqrtf(var + 1e-5f);
        }
        if (t < 128) {   // reduce 16-panel partials for this n-tile
            float u = 0.f, v = 0.f;
            #pragma unroll
            for (int kg = 0; kg < 16; ++kg) {
                u += bias0[kg * 512 + n0 + t];
                v += bias1[kg * 512 + n0 + t];
            }
            uL[t] = u; vbL[t] = v;
        }
    }

    // A staging pointers
    const ushort_t* agp[ACH];   // MODE 1
    const float*    axp[APF];   // MODE 0
    int             adst[APF];  // MODE 0 linear LDS byte offsets
    if (MODE == 0) {
        #pragma unroll
        for (int i = 0; i < APF; ++i) {
            const int p = i * 256 + t;            // 16B piece id, 0..BM*16-1
            const int row = p >> 4, u16 = p & 15;
            axp[i]  = Af + (size_t)(m0 + row) * 512 + ((u16 ^ (row & 7)) << 2);
            adst[i] = p * 16;
        }
    } else {
        #pragma unroll
        for (int i = 0; i < ACH; ++i) {
            int row = (t >> 3) + 32 * i, slot = (t & 7) ^ (row & 7);
            agp[i] = A + (size_t)(m0 + row) * 512 + slot * 8;
        }
    }
    const ushort_t* bgp[4];
    #pragma unroll
    for (int i = 0; i < 4; ++i) {
        int row = (t >> 3) + 32 * i, slot = (t & 7) ^ (row & 7);
        bgp[i] = Bt + (size_t)(n0 + row) * 512 + slot * 8;
    }

    // fragment read offsets
    int aoff[MF][2];            // MODE 1 (bf16 rows, 128B stride)
    int aoffF[MF][2][2];        // MODE 0 (f32 rows, 256B stride, 2x b128)
    #pragma unroll
    for (int mi = 0; mi < MF; ++mi)
        #pragma unroll
        for (int kh = 0; kh < 2; ++kh) {
            const int row = wr * WROWS + mi * 16 + l15;
            if (MODE == 0) {
                #pragma unroll
                for (int pr = 0; pr < 2; ++pr)
                    aoffF[mi][kh][pr] =
                        row * 256 + ((((kh * 4 + hi) * 2 + pr) ^ (row & 7)) << 4);
            } else {
                aoff[mi][kh] = row * 128 + (((kh * 4 + hi) ^ (row & 7)) * 16);
            }
        }
    int boff[4][2];
    #pragma unroll
    for (int nj = 0; nj < 4; ++nj)
        #pragma unroll
        for (int kh = 0; kh < 2; ++kh) {
            int row = wc * 64 + nj * 16 + l15;
            boff[nj][kh] = row * 128 + (((kh * 4 + hi) ^ (row & 7)) * 16);
        }

    f32x4 acc[MF][4];
    #pragma unroll
    for (int mi = 0; mi < MF; ++mi)
        #pragma unroll
        for (int nj = 0; nj < 4; ++nj)
            acc[mi][nj] = f32x4{0.f, 0.f, 0.f, 0.f};

    for (int k0 = 0; k0 < 512; k0 += 64) {
        __syncthreads();
        if (MODE == 0) {
            #pragma unroll
            for (int i = 0; i < APF; ++i)
                gl_lds16(axp[i] + k0, (char*)As + adst[i]);
        } else {
            #pragma unroll
            for (int i = 0; i < ACH; ++i)
                gl_lds16(agp[i] + k0, (char*)As + (size_t)(i * 256 + t) * 16);
        }
        #pragma unroll
        for (int i = 0; i < 4; ++i)
            gl_lds16(bgp[i] + k0, (char*)Bs + (size_t)(i * 256 + t) * 16);
        __syncthreads();
        #pragma unroll
        for (int kh = 0; kh < 2; ++kh) {
            bf16x8 af[MF], bfr[4];
            #pragma unroll
            for (int mi = 0; mi < MF; ++mi) {
                if (MODE == 0) {
                    f32x4 a0 = *(const f32x4*)((const char*)As + aoffF[mi][kh][0]);
                    f32x4 a1 = *(const f32x4*)((const char*)As + aoffF[mi][kh][1]);
                    ushort8 u = {f2b(a0[0]), f2b(a0[1]), f2b(a0[2]), f2b(a0[3]),
                                 f2b(a1[0]), f2b(a1[1]), f2b(a1[2]), f2b(a1[3])};
                    af[mi] = *(bf16x8*)&u;
                } else {
                    af[mi] = *(const bf16x8*)((const char*)As + aoff[mi][kh]);
                }
            }
            #pragma unroll
            for (int nj = 0; nj < 4; ++nj)
                bfr[nj] = *(const bf16x8*)((const char*)Bs + boff[nj][kh]);
            #pragma unroll
            for (int mi = 0; mi < MF; ++mi)
                #pragma unroll
                for (int nj = 0; nj < 4; ++nj)
                    acc[mi][nj] = __builtin_amdgcn_mfma_f32_16x16x32_bf16(
                        af[mi], bfr[nj], acc[mi][nj], 0, 0, 0);
        }
    }

    #pragma unroll
    for (int nj = 0; nj < 4; ++nj) {
        const int gcol = n0 + wc * 64 + nj * 16 + l15;
        if (MODE == 0) {
            const float bsv = (gcol < 512) ? bias0[gcol] : bias1[gcol - 512];
            #pragma unroll
            for (int mi = 0; mi < MF; ++mi)
                #pragma unroll
                for (int r = 0; r < 4; ++r) {
                    const int grow = m0 + wr * WROWS + mi * 16 + hi * 4 + r;
                    float v = acc[mi][nj][r] + bsv;
                    if (gcol < 512)
                        outH[(size_t)grow * 512 + gcol] = __float2bfloat16(tanhf(v));
                    else
                        outV[(size_t)grow * 512 + (gcol - 512)] = __float2bfloat16(v);
                }
        } else {
            const int lc = wc * 64 + nj * 16 + l15;
            const float uN = uL[lc], vbN = vbL[lc];
            #pragma unroll
            for (int mi = 0; mi < MF; ++mi)
                #pragma unroll
                for (int r = 0; r < 4; ++r) {
                    const int rl = wr * WROWS + mi * 16 + hi * 4 + r;
                    const int grow = m0 + rl;
                    const float rs = rsL[rl], mu = muL[rl];
                    outF[(size_t)grow * 512 + gcol] =
                        resid[(size_t)grow * 512 + gcol]
                        + rs * acc[mi][nj][r] - rs * mu * uN + vbN;
                }
        }
    }
}

// ---------------------------------------------------------------------------
// VT layout (scanA/scanC): [256 d-rows][64 halfwords], data in octets 0..3,
// octet XOR-swizzled with (row>>3)&7: write ~4-way, read ~8-way (vs the old
// 32-way write conflict of the pad-40 layout).
// ---------------------------------------------------------------------------

// Scan pass A (MFMA) with fused phase computation.
__global__ __launch_bounds__(256) void scanA(const __hip_bfloat16* __restrict__ Vb,
                                             const __hip_bfloat16* __restrict__ Hb,
                                             const __hip_bfloat16* __restrict__ W2T,
                                             const float* __restrict__ b2,
                                             const float* __restrict__ ps_p,
                                             const float* __restrict__ cs_p,
                                             ushort_t* __restrict__ CSg,
                                             ushort_t* __restrict__ PPg)
{
    __shared__ __align__(16) ushort_t regA[256 * 64 + 2 * 32 * 40 + 32 * 64];
    __shared__ __align__(16) ushort_t regB[32 * 520];
    ushort_t* Hs  = regA;                     // [32][520] (phase only)
    ushort_t* VT  = regA;                     // [256][64] swizzled
    ushort_t* CT  = regA + 256 * 64;          // [32][40]
    ushort_t* ST  = regA + 256 * 64 + 32 * 40;
    ushort_t* CSs = regA + 256 * 64 + 2 * 32 * 40;   // [32][64] swizzled
    ushort_t* W2L = regB;                     // [32][520]
    ushort_t* PPs = regB;                     // [256][64]

    const int t = threadIdx.x;
    const int bch = blockIdx.x, dh = blockIdx.y;
    const int b = bch >> 6, ch = bch & 63;
    const size_t vbase = ((size_t)b * LL + ch * 32) * DD + dh * 256;
    const int w = t >> 6, l = t & 63, l15 = l & 15, hi = l >> 4;

    // ---- stage1: Hs + W2L ----
    {
        const ushort8* hsrc = (const ushort8*)((const ushort_t*)Hb
                               + ((size_t)b * LL + ch * 32) * DD);
        const ushort8* wsrc = (const ushort8*)((const ushort_t*)W2T);
        #pragma unroll
        for (int i = 0; i < 8; ++i) {
            const int id = i * 256 + t;
            const int row = id >> 6, c8 = id & 63;
            ushort8 hv = hsrc[id];
            ushort8 wv = wsrc[id];
            *(ushort8*)&Hs[row * 520 + c8 * 8] = hv;
            *(ushort8*)&W2L[row * 520 + c8 * 8] = wv;
        }
    }
    __syncthreads();

    // ---- phase MFMA: P[l][k] = H[l][:] . W2[:][k] ----
    f32x4 pacc[2][2];
    #pragma unroll
    for (int mt = 0; mt < 2; ++mt)
        #pragma unroll
        for (int nt = 0; nt < 2; ++nt)
            pacc[mt][nt] = f32x4{0.f,0.f,0.f,0.f};
    for (int ks = 0; ks < 16; ++ks) {
        bf16x8 af[2], bfr[2];
        #pragma unroll
        for (int mt = 0; mt < 2; ++mt)
            af[mt] = *(const bf16x8*)&Hs[(16 * mt + l15) * 520 + ks * 32 + hi * 8];
        #pragma unroll
        for (int nt = 0; nt < 2; ++nt)
            bfr[nt] = *(const bf16x8*)&W2L[(16 * nt + l15) * 520 + ks * 32 + hi * 8];
        #pragma unroll
        for (int mt = 0; mt < 2; ++mt)
            #pragma unroll
            for (int nt = 0; nt < 2; ++nt)
                pacc[mt][nt] = __builtin_amdgcn_mfma_f32_16x16x32_bf16(
                    af[mt], bfr[nt], pacc[mt][nt], 0, 0, 0);
    }
    __syncthreads();   // Hs/W2L dead

    // ---- phases -> c,s; CT/ST (+ CSs if dh==0) ----
    {
        const float psv = ps_p[0], csv = cs_p[0];
        #pragma unroll
        for (int nt = 0; nt < 2; ++nt) {
            const int kk = l15 + 16 * nt;
            const float freq = exp2f(-(float)kk * (13.287712379549449f / (float)KK));
            const float b2k = b2[kk];
            #pragma unroll
            for (int mt = 0; mt < 2; ++mt) {
                ushort_t cw[4], sw[4];
                #pragma unroll
                for (int r = 0; r < 4; ++r) {
                    const int lloc = 16 * mt + hi * 4 + r;
                    const int lpos = ch * 32 + lloc;
                    const float content = tanhf(pacc[mt][nt][r] + b2k)
                                          * 3.14159265358979323846f * csv;
                    const float total = psv * ((float)lpos * freq) + content;
                    float sv, cv;
                    sincosf(total, &sv, &cv);
                    cw[r] = f2b(cv); sw[r] = f2b(sv);
                    if (dh == 0) {
                        CSs[lloc * 64 + (((kk >> 3) ^ (lloc & 7)) << 3) + (kk & 7)] = cw[r];
                        CSs[lloc * 64 + ((((kk >> 3) + 4) ^ (lloc & 7)) << 3) + (kk & 7)] = sw[r];
                    }
                }
                *(ushort4*)&CT[kk * 40 + 16 * mt + hi * 4] = *(ushort4*)cw;
                *(ushort4*)&ST[kk * 40 + 16 * mt + hi * 4] = *(ushort4*)sw;
            }
        }
    }
    // ---- stage VT (V^T, swizzled-octet rows) ----
    {
        const int lg = t >> 5, dg = t & 31;
        ushort8 r[4];
        #pragma unroll
        for (int i = 0; i < 4; ++i)
            r[i] = *(const ushort8*)((const ushort_t*)Vb + vbase
                                     + (size_t)(lg * 4 + i) * DD + dg * 8);
        const int oct = (lg >> 1) ^ (dg & 7);
        const int sub = (lg & 1) * 4;
        #pragma unroll
        for (int jd = 0; jd < 8; ++jd) {
            ushort4 w4 = {r[0][jd], r[1][jd], r[2][jd], r[3][jd]};
            *(ushort4*)&VT[(dg * 8 + jd) * 64 + oct * 8 + sub] = w4;
        }
    }
    __syncthreads();

    if (dh == 0) {   // coalesced CS copyout (4 KB)
        ushort_t* cso = CSg + ((size_t)b * NCH + ch) * 2048;
        *(ushort8*)(cso + t * 8) = *(const ushort8*)&CSs[t * 8];
    }

    // ---- PP MFMA ----
    bf16x8 afc[2], afs[2];
    #pragma unroll
    for (int mt = 0; mt < 2; ++mt) {
        afc[mt] = *(const bf16x8*)&CT[(l15 + 16 * mt) * 40 + hi * 8];
        afs[mt] = *(const bf16x8*)&ST[(l15 + 16 * mt) * 40 + hi * 8];
    }
    f32x4 aPR[2][4], aPI[2][4];
    #pragma unroll
    for (int mt = 0; mt < 2; ++mt)
        #pragma unroll
        for (int nt = 0; nt < 4; ++nt) {
            aPR[mt][nt] = f32x4{0.f,0.f,0.f,0.f};
            aPI[mt][nt] = f32x4{0.f,0.f,0.f,0.f};
        }
    #pragma unroll
    for (int nt = 0; nt < 4; ++nt) {
        const int drow = w * 64 + nt * 16 + l15;
        bf16x8 bv = *(const bf16x8*)&VT[drow * 64 + ((hi ^ ((drow >> 3) & 7)) << 3)];
        #pragma unroll
        for (int mt = 0; mt < 2; ++mt) {
            aPR[mt][nt] = __builtin_amdgcn_mfma_f32_16x16x32_bf16(afc[mt], bv, aPR[mt][nt], 0,0,0);
            aPI[mt][nt] = __builtin_amdgcn_mfma_f32_16x16x32_bf16(afs[mt], bv, aPI[mt][nt], 0,0,0);
        }
    }
    // transpose to [d][kk] bf16 (swizzled octets), coalesced copyout
    #pragma unroll
    for (int mt = 0; mt < 2; ++mt)
        #pragma unroll
        for (int nt = 0; nt < 4; ++nt) {
            const int dloc = w * 64 + nt * 16 + l15;
            const int kq = 16 * mt + hi * 4;
            const int oR = kq >> 3, oI = 4 + (kq >> 3);
            const int sub = (hi & 1) * 4;
            ushort4 pr4 = {f2b(aPR[mt][nt][0]), f2b(aPR[mt][nt][1]),
                           f2b(aPR[mt][nt][2]), f2b(aPR[mt][nt][3])};
            ushort4 pi4 = {f2b(aPI[mt][nt][0]), f2b(aPI[mt][nt][1]),
                           f2b(aPI[mt][nt][2]), f2b(aPI[mt][nt][3])};
            *(ushort4*)&PPs[dloc * 64 + ((oR ^ (dloc & 7)) * 8) + sub] = pr4;
            *(ushort4*)&PPs[dloc * 64 + ((oI ^ (dloc & 7)) * 8) + sub] = pi4;
        }
    __syncthreads();
    ushort_t* gout = PPg + ((size_t)bch * 512 + dh * 256) * 64;
    #pragma unroll
    for (int i = 0; i < 8; ++i)
        *(ushort8*)(gout + (size_t)(i * 256 + t) * 8) =
            *(const ushort8*)&PPs[(i * 256 + t) * 8];
}

// ---------------------------------------------------------------------------
// Scan pass B: exclusive prefix over 64 chunks on bf16 PP (f32 accumulate).
// ---------------------------------------------------------------------------
__global__ __launch_bounds__(256) void scan_prefix(ushort_t* __restrict__ PPg)
{
    const int g = blockIdx.x * 256 + threadIdx.x;   // 0..65535
    const int b = g >> 15, p = g & 32767;
    float run = 0.f;
    for (int gg = 0; gg < 4; ++gg) {
        ushort_t v[16];
        #pragma unroll
        for (int i = 0; i < 16; ++i)
            v[i] = PPg[(size_t)(b * 64 + gg * 16 + i) * 32768 + p];
        #pragma unroll
        for (int i = 0; i < 16; ++i) {
            ushort_t o = f2b(run);
            run += b2f(v[i]);
            PPg[(size_t)(b * 64 + gg * 16 + i) * 32768 + p] = o;
        }
    }
}

// ---------------------------------------------------------------------------
// Scan pass C (MFMA): ret = [C|S]@PPpre + tri(G)@V, scale, in-place over Vb.
// RT slab overlays the dead VT region (barrier separates).
// ---------------------------------------------------------------------------
__global__ __launch_bounds__(256) void scanC(__hip_bfloat16* Vb,
                                             const ushort_t* __restrict__ CSg,
                                             const ushort_t* __restrict__ PPg,
                                             float* __restrict__ StatsG)
{
    __shared__ __align__(16) ushort_t VT[256 * 64];   // [d][64] swizzled; RT overlay
    __shared__ __align__(16) ushort_t PPT[256 * 64];  // [d][kk], swizzled octets
    __shared__ __align__(16) ushort_t CS[32 * 64];    // [l][c|s], swizzled octets
    __shared__ __align__(16) ushort_t G[32 * 40];     // [l][l'], pad->40
    __shared__ float2 statsL[4][32];

    const int t = threadIdx.x;
    const int bch = blockIdx.x, dh = blockIdx.y;
    const int b = bch >> 6, ch = bch & 63;
    const size_t vbase = ((size_t)b * LL + ch * 32) * DD + dh * 256;

    {   // stage PPT + CS via async direct-to-LDS (pre-swizzled in global)
        const ushort_t* ppg = PPg + ((size_t)bch * 512 + dh * 256) * 64;
        #pragma unroll
        for (int i = 0; i < 8; ++i)
            gl_lds16(ppg + (size_t)(i * 256 + t) * 8,
                     (char*)PPT + (size_t)(i * 256 + t) * 16);
        const ushort_t* csg = CSg + ((size_t)b * NCH + ch) * 2048;
        gl_lds16(csg + (size_t)t * 8, (char*)CS + (size_t)t * 16);
    }
    {   // stage V^T (swizzled-octet rows)
        const int lg = t >> 5, dg = t & 31;
        ushort8 r[4];
        #pragma unroll
        for (int i = 0; i < 4; ++i)
            r[i] = *(const ushort8*)((const ushort_t*)Vb + vbase
                                     + (size_t)(lg * 4 + i) * DD + dg * 8);
        const int oct = (lg >> 1) ^ (dg & 7);
        const int sub = (lg & 1) * 4;
        #pragma unroll
        for (int jd = 0; jd < 8; ++jd) {
            ushort4 w4 = {r[0][jd], r[1][jd], r[2][jd], r[3][jd]};
            *(ushort4*)&VT[(dg * 8 + jd) * 64 + oct * 8 + sub] = w4;
        }
    }
    __syncthreads();

    const int w = t >> 6, l = t & 63, l15 = l & 15, hi = l >> 4;

    // load C/S fragments once (swizzled-octet reads)
    bf16x8 fc[2], fs[2];
    #pragma unroll
    for (int mt = 0; mt < 2; ++mt) {
        const int row = l15 + 16 * mt;
        fc[mt] = *(const bf16x8*)&CS[row * 64 + ((hi ^ (row & 7)) << 3)];
        fs[mt] = *(const bf16x8*)&CS[row * 64 + (((4 + hi) ^ (row & 7)) << 3)];
    }

    {   // G = tri(C@C^T + S@S^T)
        f32x4 gacc[2][2];
        #pragma unroll
        for (int mt = 0; mt < 2; ++mt)
            #pragma unroll
            for (int nt = 0; nt < 2; ++nt) {
                gacc[mt][nt] = f32x4{0.f,0.f,0.f,0.f};
                gacc[mt][nt] = __builtin_amdgcn_mfma_f32_16x16x32_bf16(fc[mt], fc[nt], gacc[mt][nt], 0,0,0);
                gacc[mt][nt] = __builtin_amdgcn_mfma_f32_16x16x32_bf16(fs[mt], fs[nt], gacc[mt][nt], 0,0,0);
            }
        #pragma unroll
        for (int mt = 0; mt < 2; ++mt)
            #pragma unroll
            for (int nt = 0; nt < 2; ++nt)
                #pragma unroll
                for (int r = 0; r < 4; ++r) {
                    const int row = 16 * mt + hi * 4 + r;
                    const int col = 16 * nt + l15;
                    float gv = (col <= row) ? gacc[mt][nt][r] : 0.f;
                    G[row * 40 + col] = f2b(gv);
                }
    }

    bf16x8 ag[2];
    #pragma unroll
    for (int mt = 0; mt < 2; ++mt)
        ag[mt] = *(const bf16x8*)&G[(l15 + 16 * mt) * 40 + hi * 8];

    f32x4 acc[2][4];
    #pragma unroll
    for (int mt = 0; mt < 2; ++mt)
        #pragma unroll
        for (int nt = 0; nt < 4; ++nt)
            acc[mt][nt] = f32x4{0.f,0.f,0.f,0.f};
    #pragma unroll
    for (int nt = 0; nt < 4; ++nt) {
        const int drow = w * 64 + nt * 16 + l15;
        bf16x8 bp0 = *(const bf16x8*)((const char*)PPT + drow * 128 + ((hi ^ (drow & 7)) << 4));
        bf16x8 bp1 = *(const bf16x8*)((const char*)PPT + drow * 128 + (((4 + hi) ^ (drow & 7)) << 4));
        bf16x8 bv  = *(const bf16x8*)&VT[drow * 64 + ((hi ^ ((drow >> 3) & 7)) << 3)];
        #pragma unroll
        for (int mt = 0; mt < 2; ++mt) {
            acc[mt][nt] = __builtin_amdgcn_mfma_f32_16x16x32_bf16(fc[mt], bp0, acc[mt][nt], 0,0,0);
            acc[mt][nt] = __builtin_amdgcn_mfma_f32_16x16x32_bf16(fs[mt], bp1, acc[mt][nt], 0,0,0);
            acc[mt][nt] = __builtin_amdgcn_mfma_f32_16x16x32_bf16(ag[mt], bv,  acc[mt][nt], 0,0,0);
        }
    }

    __syncthreads();   // VT reads complete in all waves; RT overlays VT region
    ushort_t* RTw = VT + w * 2048;     // per-wave [32][64] slab

    float sP[2][4] = {}, qP[2][4] = {};
    #pragma unroll
    for (int mt = 0; mt < 2; ++mt)
        #pragma unroll
        for (int nt = 0; nt < 4; ++nt)
            #pragma unroll
            for (int r = 0; r < 4; ++r) {
                const int lrow = 16 * mt + hi * 4 + r;
                const float scale = rsqrtf((float)((ch * 32 + lrow + 1) * KK));
                const float val = acc[mt][nt][r] * scale;
                sP[mt][r] += val;
                qP[mt][r] = fmaf(val, val, qP[mt][r]);
                RTw[lrow * 64 + nt * 16 + l15] = f2b(val);
            }
    #pragma unroll
    for (int c = 0; c < 4; ++c) {
        const int cid = c * 64 + l;
        const int row = cid >> 3, c8 = cid & 7;
        ushort8 v = *(const ushort8*)&RTw[row * 64 + c8 * 8];
        *(ushort8*)((ushort_t*)Vb + ((size_t)b * LL + ch * 32 + row) * DD
                    + dh * 256 + w * 64 + c8 * 8) = v;
    }
    #pragma unroll
    for (int mt = 0; mt < 2; ++mt)
        #pragma unroll
        for (int r = 0; r < 4; ++r) {
            float sv = sP[mt][r], qv = qP[mt][r];
            #pragma unroll
            for (int off = 1; off < 16; off <<= 1) {
                sv += __shfl_xor(sv, off);
                qv += __shfl_xor(qv, off);
            }
            if (l15 == 0)
                statsL[w][16 * mt + hi * 4 + r] = float2{sv, qv};
        }
    __syncthreads();
    if (t < 32) {
        float s = 0.f, q = 0.f;
        #pragma unroll
        for (int w4 = 0; w4 < 4; ++w4) {
            float2 p = statsL[w4][t];
            s += p.x; q += p.y;
        }
        const size_t rowg = (size_t)b * LL + ch * 32 + t;
        *(float2*)&StatsG[(rowg * 2 + dh) * 2] = float2{s, q};
    }
}

// ---------------------------------------------------------------------------
extern "C" void kernel_launch(void* const* d_in, const int* in_sizes, int n_in,
                              void* d_out, int out_size, void* d_ws, size_t ws_size,
                              hipStream_t stream)
{
    const float* x   = (const float*)d_in[0];
    const float* W1  = (const float*)d_in[1];
    const float* b1  = (const float*)d_in[2];
    const float* W2  = (const float*)d_in[3];
    const float* b2  = (const float*)d_in[4];
    const float* ps  = (const float*)d_in[5];
    const float* cs  = (const float*)d_in[6];
    const float* Wv  = (const float*)d_in[7];
    const float* bv  = (const float*)d_in[8];
    const float* lng = (const float*)d_in[9];
    const float* lnb = (const float*)d_in[10];
    const float* Wo  = (const float*)d_in[11];
    const float* bo  = (const float*)d_in[12];
    float* out = (float*)d_out;

    char* wsb = (char*)d_ws;
    __hip_bfloat16* Vb  = (__hip_bfloat16*)(wsb);                     // 4 MB
    ushort_t* PPg = (ushort_t*)(wsb + (4u << 20));                    // 8 MB
    ushort_t* CSg = (ushort_t*)(wsb + (12u << 20));                   // 512 KB
    __hip_bfloat16* Hb  = (__hip_bfloat16*)(wsb + (13u << 20));       // 4 MB
    __hip_bfloat16* Wct = (__hip_bfloat16*)(wsb + (17u << 20));       // 1 MB
    __hip_bfloat16* Wot = (__hip_bfloat16*)(wsb + (18u << 20));       // 0.5 MB
    float* StatsG = (float*)(wsb + (19u << 20));                      // 64 KB
    float* Upart  = (float*)(wsb + (19u << 20) + (64u << 10));        // 32 KB
    float* Vpart  = (float*)(wsb + (19u << 20) + (96u << 10));        // 32 KB
    __hip_bfloat16* W2T = (__hip_bfloat16*)(wsb + (19u << 20) + (128u << 10)); // 32 KB

    prep<<<dim3(16, 16, 5), dim3(32, 8), 0, stream>>>(
        W1, Wv, Wo, W2, lng, lnb, bo, Wct, Wot, W2T, Upart, Vpart);
    gemm_mfma<64, 0><<<dim3(8, 64), dim3(256), 0, stream>>>(
        nullptr, x, (const ushort_t*)Wct, b1, bv, nullptr, Hb, Vb, nullptr, nullptr);
    scanA<<<dim3(BB * NCH, 2), dim3(256), 0, stream>>>(
        Vb, Hb, W2T, b2, ps, cs, CSg, PPg);
    scan_prefix<<<dim3(256), dim3(256), 0, stream>>>(PPg);
    scanC<<<dim3(BB * NCH, 2), dim3(256), 0, stream>>>(Vb, CSg, PPg, StatsG);
    gemm_mfma<32, 1><<<dim3(4, 128), dim3(256), 0, stream>>>(
        (const ushort_t*)Vb, nullptr, (const ushort_t*)Wot, Upart, Vpart, x,
        nullptr, nullptr, out, StatsG);
}

// Round 13
// 58.621 us; speedup vs baseline: 1.0332x; 1.0332x over previous
//
#include <hip/hip_runtime.h>
#include <hip/hip_bf16.h>
#include <math.h>

// Problem constants
#define BB   2
#define LL   2048
#define DD   512
#define KK   32
#define BL   (BB*LL)      // 4096
#define NCH  64           // chunks along L

typedef unsigned short ushort_t;
typedef __bf16 bf16x8 __attribute__((ext_vector_type(8)));
typedef float  f32x4  __attribute__((ext_vector_type(4)));
typedef unsigned short ushort8 __attribute__((ext_vector_type(8)));

__device__ __forceinline__ void gl_lds16(const void* g, void* l) {
    __builtin_amdgcn_global_load_lds(
        (const __attribute__((address_space(1))) void*)g,
        (__attribute__((address_space(3))) void*)l, 16, 0, 0);
}
__device__ __forceinline__ ushort_t f2b(float f) {
    __bf16 b = (__bf16)f; return *(ushort_t*)&b;
}
__device__ __forceinline__ float b2f(ushort_t u) {
    unsigned int x = ((unsigned int)u) << 16; return *(float*)&x;
}

// ---------------------------------------------------------------------------
// prep: z=0: W1^T->Wct[0:512]; z=1: Wv^T->Wct[512:]; z=2: (g.Wo)^T->Wot;
//       z=3: cast x->xb; z=4: Upart/Vpart[kg][n] partial GEMV (no atomics);
//       z=5: W2^T -> W2T bf16 [32][512]
// ---------------------------------------------------------------------------
__global__ __launch_bounds__(256) void prep(const float* __restrict__ W1,
                                            const float* __restrict__ Wv,
                                            const float* __restrict__ Wo,
                                            const float* __restrict__ W2,
                                            const float* __restrict__ x,
                                            const float* __restrict__ lng,
                                            const float* __restrict__ lnb,
                                            const float* __restrict__ bo,
                                            __hip_bfloat16* __restrict__ Wct,
                                            __hip_bfloat16* __restrict__ Wot,
                                            __hip_bfloat16* __restrict__ W2T,
                                            __hip_bfloat16* __restrict__ xb,
                                            float* __restrict__ Upart,
                                            float* __restrict__ Vpart)
{
    __shared__ float tile[32][33];
    const int bz = blockIdx.z;
    const int tx = threadIdx.x, ty = threadIdx.y;
    const int t = ty * 32 + tx;

    if (bz == 3) {                      // cast x (2M floats): 256 blocks
        const int bid = blockIdx.y * 16 + blockIdx.x;
        const float4* src = (const float4*)x + (size_t)bid * 2048 + t;
        ushort4* dst = (ushort4*)xb + (size_t)bid * 2048 + t;
        #pragma unroll
        for (int i = 0; i < 8; ++i) {
            float4 v = src[i * 256];
            ushort4 o = {f2b(v.x), f2b(v.y), f2b(v.z), f2b(v.w)};
            dst[i * 256] = o;
        }
        return;
    }
    if (bz == 4) {                      // Upart/Vpart: 16 k-panel blocks
        if (blockIdx.x != 0) return;
        const int kg = blockIdx.y;      // 0..15
        const int k0 = kg * 32;
        float u0 = 0.f, u1 = 0.f, v0 = 0.f, v1 = 0.f;
        #pragma unroll 4
        for (int k = 0; k < 32; ++k) {
            const float g1 = lng[k0 + k], b1v = lnb[k0 + k];
            const float w0 = Wo[(size_t)(k0 + k) * 512 + t];
            const float w1 = Wo[(size_t)(k0 + k) * 512 + t + 256];
            u0 = fmaf(g1, w0, u0);  u1 = fmaf(g1, w1, u1);
            v0 = fmaf(b1v, w0, v0); v1 = fmaf(b1v, w1, v1);
        }
        if (kg == 0) { v0 += bo[t]; v1 += bo[t + 256]; }
        Upart[kg * 512 + t] = u0;       Upart[kg * 512 + t + 256] = u1;
        Vpart[kg * 512 + t] = v0;       Vpart[kg * 512 + t + 256] = v1;
        return;
    }
    if (bz == 5) {                      // W2 [512][32] -> W2T bf16 [32][512]
        if (blockIdx.x != 0) return;
        const int r0 = blockIdx.y * 32;       // d-rows
        #pragma unroll
        for (int i = 0; i < 4; ++i)
            tile[ty + 8 * i][tx] = W2[(size_t)(r0 + ty + 8 * i) * 32 + tx];
        __syncthreads();
        #pragma unroll
        for (int i = 0; i < 4; ++i)
            W2T[(size_t)(ty + 8 * i) * 512 + r0 + tx] =
                __float2bfloat16(tile[tx][ty + 8 * i]);
        return;
    }
    // transpose planes 0..2
    const float* src = bz == 0 ? W1 : (bz == 1 ? Wv : Wo);
    __hip_bfloat16* dst = bz == 0 ? Wct
                        : (bz == 1 ? Wct + 512 * 512 : Wot);
    const int r0 = blockIdx.y * 32, c0 = blockIdx.x * 32;
    #pragma unroll
    for (int i = 0; i < 4; ++i)
        tile[ty + 8 * i][tx] = src[(size_t)(r0 + ty + 8 * i) * 512 + c0 + tx];
    __syncthreads();
    const float sc = (bz == 2) ? lng[r0 + tx] : 1.f;
    #pragma unroll
    for (int i = 0; i < 4; ++i)
        dst[(size_t)(c0 + ty + 8 * i) * 512 + r0 + tx] =
            __float2bfloat16(tile[tx][ty + 8 * i] * sc);
}

// ---------------------------------------------------------------------------
// bf16 MFMA GEMM: C[M,N] = A[M,512] @ Bt[N,512]^T, BM x 128 tile, 4 waves.
// A and B both staged via global_load_lds (pre-swizzled global source).
// MODE 0: cols<512 -> outH = bf16(tanh(.+b0)); cols>=512 -> outV = bf16(.+b1)
// MODE 1: fused-LN epilogue: out = resid + rs*. - rs*mu*U[col] + VBc[col]
//         (bias0/bias1 = Upart/Vpart 16-panel partials, reduced in prologue)
// ---------------------------------------------------------------------------
template<int BM, int MODE>
__global__ __launch_bounds__(256) void gemm_mfma(
    const ushort_t* __restrict__ A, const ushort_t* __restrict__ Bt,
    const float* __restrict__ bias0, const float* __restrict__ bias1,
    const float* __restrict__ resid,
    __hip_bfloat16* __restrict__ outH, __hip_bfloat16* __restrict__ outV,
    float* __restrict__ outF, const float* __restrict__ stats)
{
    constexpr int WROWS = BM / 2;
    constexpr int MF    = WROWS / 16;
    constexpr int ACH   = BM / 32;
    __shared__ __align__(16) ushort_t As[BM * 64];
    __shared__ __align__(16) ushort_t Bs[128 * 64];
    __shared__ float muL[BM], rsL[BM], uL[128], vbL[128];

    const int t  = threadIdx.x;
    const int m0 = blockIdx.y * BM, n0 = blockIdx.x * 128;
    const int l  = t & 63, w = t >> 6;
    const int wr = w >> 1, wc = w & 1;
    const int l15 = l & 15, hi = l >> 4;

    if (MODE == 1) {
        if (t < BM) {
            float4 st = *(const float4*)(stats + (size_t)(m0 + t) * 4);
            float s = st.x + st.z, s2 = st.y + st.w;
            float mu = s * (1.f / 512), var = s2 * (1.f / 512) - mu * mu;
            muL[t] = mu;
            rsL[t] = rsqrtf(var + 1e-5f);
        }
        if (t < 128) {   // reduce 16-panel partials for this n-tile
            float u = 0.f, v = 0.f;
            #pragma unroll
            for (int kg = 0; kg < 16; ++kg) {
                u += bias0[kg * 512 + n0 + t];
                v += bias1[kg * 512 + n0 + t];
            }
            uL[t] = u; vbL[t] = v;
        }
    }

    const ushort_t* agp[ACH];
    const ushort_t* bgp[4];
    #pragma unroll
    for (int i = 0; i < ACH; ++i) {
        int row = (t >> 3) + 32 * i, slot = (t & 7) ^ (row & 7);
        agp[i] = A + (size_t)(m0 + row) * 512 + slot * 8;
    }
    #pragma unroll
    for (int i = 0; i < 4; ++i) {
        int row = (t >> 3) + 32 * i, slot = (t & 7) ^ (row & 7);
        bgp[i] = Bt + (size_t)(n0 + row) * 512 + slot * 8;
    }

    int aoff[MF][2], boff[4][2];
    #pragma unroll
    for (int mi = 0; mi < MF; ++mi)
        #pragma unroll
        for (int kh = 0; kh < 2; ++kh) {
            int row = wr * WROWS + mi * 16 + l15;
            aoff[mi][kh] = row * 128 + (((kh * 4 + hi) ^ (row & 7)) * 16);
        }
    #pragma unroll
    for (int nj = 0; nj < 4; ++nj)
        #pragma unroll
        for (int kh = 0; kh < 2; ++kh) {
            int row = wc * 64 + nj * 16 + l15;
            boff[nj][kh] = row * 128 + (((kh * 4 + hi) ^ (row & 7)) * 16);
        }

    f32x4 acc[MF][4];
    #pragma unroll
    for (int mi = 0; mi < MF; ++mi)
        #pragma unroll
        for (int nj = 0; nj < 4; ++nj)
            acc[mi][nj] = f32x4{0.f, 0.f, 0.f, 0.f};

    for (int k0 = 0; k0 < 512; k0 += 64) {
        __syncthreads();
        #pragma unroll
        for (int i = 0; i < ACH; ++i)
            gl_lds16(agp[i] + k0, (char*)As + (size_t)(i * 256 + t) * 16);
        #pragma unroll
        for (int i = 0; i < 4; ++i)
            gl_lds16(bgp[i] + k0, (char*)Bs + (size_t)(i * 256 + t) * 16);
        __syncthreads();
        #pragma unroll
        for (int kh = 0; kh < 2; ++kh) {
            bf16x8 af[MF], bfr[4];
            #pragma unroll
            for (int mi = 0; mi < MF; ++mi)
                af[mi] = *(const bf16x8*)((const char*)As + aoff[mi][kh]);
            #pragma unroll
            for (int nj = 0; nj < 4; ++nj)
                bfr[nj] = *(const bf16x8*)((const char*)Bs + boff[nj][kh]);
            #pragma unroll
            for (int mi = 0; mi < MF; ++mi)
                #pragma unroll
                for (int nj = 0; nj < 4; ++nj)
                    acc[mi][nj] = __builtin_amdgcn_mfma_f32_16x16x32_bf16(
                        af[mi], bfr[nj], acc[mi][nj], 0, 0, 0);
        }
    }

    #pragma unroll
    for (int nj = 0; nj < 4; ++nj) {
        const int gcol = n0 + wc * 64 + nj * 16 + l15;
        if (MODE == 0) {
            const float bsv = (gcol < 512) ? bias0[gcol] : bias1[gcol - 512];
            #pragma unroll
            for (int mi = 0; mi < MF; ++mi)
                #pragma unroll
                for (int r = 0; r < 4; ++r) {
                    const int grow = m0 + wr * WROWS + mi * 16 + hi * 4 + r;
                    float v = acc[mi][nj][r] + bsv;
                    if (gcol < 512)
                        outH[(size_t)grow * 512 + gcol] = __float2bfloat16(tanhf(v));
                    else
                        outV[(size_t)grow * 512 + (gcol - 512)] = __float2bfloat16(v);
                }
        } else {
            const int lc = wc * 64 + nj * 16 + l15;
            const float uN = uL[lc], vbN = vbL[lc];
            #pragma unroll
            for (int mi = 0; mi < MF; ++mi)
                #pragma unroll
                for (int r = 0; r < 4; ++r) {
                    const int rl = wr * WROWS + mi * 16 + hi * 4 + r;
                    const int grow = m0 + rl;
                    const float rs = rsL[rl], mu = muL[rl];
                    outF[(size_t)grow * 512 + gcol] =
                        resid[(size_t)grow * 512 + gcol]
                        + rs * acc[mi][nj][r] - rs * mu * uN + vbN;
                }
        }
    }
}

// ---------------------------------------------------------------------------
// VT layout (scanA/scanC): [256 d-rows][64 halfwords], data in octets 0..3,
// octet XOR-swizzled with (row>>3)&7: write ~4-way, read ~8-way (vs the old
// 32-way write conflict of the pad-40 layout).
// ---------------------------------------------------------------------------

// Scan pass A (MFMA) with fused phase computation.
__global__ __launch_bounds__(256) void scanA(const __hip_bfloat16* __restrict__ Vb,
                                             const __hip_bfloat16* __restrict__ Hb,
                                             const __hip_bfloat16* __restrict__ W2T,
                                             const float* __restrict__ b2,
                                             const float* __restrict__ ps_p,
                                             const float* __restrict__ cs_p,
                                             ushort_t* __restrict__ CSg,
                                             ushort_t* __restrict__ PPg)
{
    __shared__ __align__(16) ushort_t regA[256 * 64 + 2 * 32 * 40 + 32 * 64];
    __shared__ __align__(16) ushort_t regB[32 * 520];
    ushort_t* Hs  = regA;                     // [32][520] (phase only)
    ushort_t* VT  = regA;                     // [256][64] swizzled
    ushort_t* CT  = regA + 256 * 64;          // [32][40]
    ushort_t* ST  = regA + 256 * 64 + 32 * 40;
    ushort_t* CSs = regA + 256 * 64 + 2 * 32 * 40;   // [32][64] swizzled
    ushort_t* W2L = regB;                     // [32][520]
    ushort_t* PPs = regB;                     // [256][64]

    const int t = threadIdx.x;
    const int bch = blockIdx.x, dh = blockIdx.y;
    const int b = bch >> 6, ch = bch & 63;
    const size_t vbase = ((size_t)b * LL + ch * 32) * DD + dh * 256;
    const int w = t >> 6, l = t & 63, l15 = l & 15, hi = l >> 4;

    // ---- stage1: Hs + W2L ----
    {
        const ushort8* hsrc = (const ushort8*)((const ushort_t*)Hb
                               + ((size_t)b * LL + ch * 32) * DD);
        const ushort8* wsrc = (const ushort8*)((const ushort_t*)W2T);
        #pragma unroll
        for (int i = 0; i < 8; ++i) {
            const int id = i * 256 + t;
            const int row = id >> 6, c8 = id & 63;
            ushort8 hv = hsrc[id];
            ushort8 wv = wsrc[id];
            *(ushort8*)&Hs[row * 520 + c8 * 8] = hv;
            *(ushort8*)&W2L[row * 520 + c8 * 8] = wv;
        }
    }
    __syncthreads();

    // ---- phase MFMA: P[l][k] = H[l][:] . W2[:][k] ----
    f32x4 pacc[2][2];
    #pragma unroll
    for (int mt = 0; mt < 2; ++mt)
        #pragma unroll
        for (int nt = 0; nt < 2; ++nt)
            pacc[mt][nt] = f32x4{0.f,0.f,0.f,0.f};
    for (int ks = 0; ks < 16; ++ks) {
        bf16x8 af[2], bfr[2];
        #pragma unroll
        for (int mt = 0; mt < 2; ++mt)
            af[mt] = *(const bf16x8*)&Hs[(16 * mt + l15) * 520 + ks * 32 + hi * 8];
        #pragma unroll
        for (int nt = 0; nt < 2; ++nt)
            bfr[nt] = *(const bf16x8*)&W2L[(16 * nt + l15) * 520 + ks * 32 + hi * 8];
        #pragma unroll
        for (int mt = 0; mt < 2; ++mt)
            #pragma unroll
            for (int nt = 0; nt < 2; ++nt)
                pacc[mt][nt] = __builtin_amdgcn_mfma_f32_16x16x32_bf16(
                    af[mt], bfr[nt], pacc[mt][nt], 0, 0, 0);
    }
    __syncthreads();   // Hs/W2L dead

    // ---- phases -> c,s; CT/ST (+ CSs if dh==0) ----
    {
        const float psv = ps_p[0], csv = cs_p[0];
        #pragma unroll
        for (int nt = 0; nt < 2; ++nt) {
            const int kk = l15 + 16 * nt;
            const float freq = exp2f(-(float)kk * (13.287712379549449f / (float)KK));
            const float b2k = b2[kk];
            #pragma unroll
            for (int mt = 0; mt < 2; ++mt) {
                ushort_t cw[4], sw[4];
                #pragma unroll
                for (int r = 0; r < 4; ++r) {
                    const int lloc = 16 * mt + hi * 4 + r;
                    const int lpos = ch * 32 + lloc;
                    const float content = tanhf(pacc[mt][nt][r] + b2k)
                                          * 3.14159265358979323846f * csv;
                    const float total = psv * ((float)lpos * freq) + content;
                    float sv, cv;
                    sincosf(total, &sv, &cv);
                    cw[r] = f2b(cv); sw[r] = f2b(sv);
                    if (dh == 0) {
                        CSs[lloc * 64 + (((kk >> 3) ^ (lloc & 7)) << 3) + (kk & 7)] = cw[r];
                        CSs[lloc * 64 + ((((kk >> 3) + 4) ^ (lloc & 7)) << 3) + (kk & 7)] = sw[r];
                    }
                }
                *(ushort4*)&CT[kk * 40 + 16 * mt + hi * 4] = *(ushort4*)cw;
                *(ushort4*)&ST[kk * 40 + 16 * mt + hi * 4] = *(ushort4*)sw;
            }
        }
    }
    // ---- stage VT (V^T, swizzled-octet rows) ----
    {
        const int lg = t >> 5, dg = t & 31;
        ushort8 r[4];
        #pragma unroll
        for (int i = 0; i < 4; ++i)
            r[i] = *(const ushort8*)((const ushort_t*)Vb + vbase
                                     + (size_t)(lg * 4 + i) * DD + dg * 8);
        const int oct = (lg >> 1) ^ (dg & 7);
        const int sub = (lg & 1) * 4;
        #pragma unroll
        for (int jd = 0; jd < 8; ++jd) {
            ushort4 w4 = {r[0][jd], r[1][jd], r[2][jd], r[3][jd]};
            *(ushort4*)&VT[(dg * 8 + jd) * 64 + oct * 8 + sub] = w4;
        }
    }
    __syncthreads();

    if (dh == 0) {   // coalesced CS copyout (4 KB)
        ushort_t* cso = CSg + ((size_t)b * NCH + ch) * 2048;
        *(ushort8*)(cso + t * 8) = *(const ushort8*)&CSs[t * 8];
    }

    // ---- PP MFMA ----
    bf16x8 afc[2], afs[2];
    #pragma unroll
    for (int mt = 0; mt < 2; ++mt) {
        afc[mt] = *(const bf16x8*)&CT[(l15 + 16 * mt) * 40 + hi * 8];
        afs[mt] = *(const bf16x8*)&ST[(l15 + 16 * mt) * 40 + hi * 8];
    }
    f32x4 aPR[2][4], aPI[2][4];
    #pragma unroll
    for (int mt = 0; mt < 2; ++mt)
        #pragma unroll
        for (int nt = 0; nt < 4; ++nt) {
            aPR[mt][nt] = f32x4{0.f,0.f,0.f,0.f};
            aPI[mt][nt] = f32x4{0.f,0.f,0.f,0.f};
        }
    #pragma unroll
    for (int nt = 0; nt < 4; ++nt) {
        const int drow = w * 64 + nt * 16 + l15;
        bf16x8 bv = *(const bf16x8*)&VT[drow * 64 + ((hi ^ ((drow >> 3) & 7)) << 3)];
        #pragma unroll
        for (int mt = 0; mt < 2; ++mt) {
            aPR[mt][nt] = __builtin_amdgcn_mfma_f32_16x16x32_bf16(afc[mt], bv, aPR[mt][nt], 0,0,0);
            aPI[mt][nt] = __builtin_amdgcn_mfma_f32_16x16x32_bf16(afs[mt], bv, aPI[mt][nt], 0,0,0);
        }
    }
    // transpose to [d][kk] bf16 (swizzled octets), coalesced copyout
    #pragma unroll
    for (int mt = 0; mt < 2; ++mt)
        #pragma unroll
        for (int nt = 0; nt < 4; ++nt) {
            const int dloc = w * 64 + nt * 16 + l15;
            const int kq = 16 * mt + hi * 4;
            const int oR = kq >> 3, oI = 4 + (kq >> 3);
            const int sub = (hi & 1) * 4;
            ushort4 pr4 = {f2b(aPR[mt][nt][0]), f2b(aPR[mt][nt][1]),
                           f2b(aPR[mt][nt][2]), f2b(aPR[mt][nt][3])};
            ushort4 pi4 = {f2b(aPI[mt][nt][0]), f2b(aPI[mt][nt][1]),
                           f2b(aPI[mt][nt][2]), f2b(aPI[mt][nt][3])};
            *(ushort4*)&PPs[dloc * 64 + ((oR ^ (dloc & 7)) * 8) + sub] = pr4;
            *(ushort4*)&PPs[dloc * 64 + ((oI ^ (dloc & 7)) * 8) + sub] = pi4;
        }
    __syncthreads();
    ushort_t* gout = PPg + ((size_t)bch * 512 + dh * 256) * 64;
    #pragma unroll
    for (int i = 0; i < 8; ++i)
        *(ushort8*)(gout + (size_t)(i * 256 + t) * 8) =
            *(const ushort8*)&PPs[(i * 256 + t) * 8];
}

// ---------------------------------------------------------------------------
// Scan pass B: exclusive prefix over 64 chunks on bf16 PP (f32 accumulate).
// ---------------------------------------------------------------------------
__global__ __launch_bounds__(256) void scan_prefix(ushort_t* __restrict__ PPg)
{
    const int g = blockIdx.x * 256 + threadIdx.x;   // 0..65535
    const int b = g >> 15, p = g & 32767;
    float run = 0.f;
    for (int gg = 0; gg < 4; ++gg) {
        ushort_t v[16];
        #pragma unroll
        for (int i = 0; i < 16; ++i)
            v[i] = PPg[(size_t)(b * 64 + gg * 16 + i) * 32768 + p];
        #pragma unroll
        for (int i = 0; i < 16; ++i) {
            ushort_t o = f2b(run);
            run += b2f(v[i]);
            PPg[(size_t)(b * 64 + gg * 16 + i) * 32768 + p] = o;
        }
    }
}

// ---------------------------------------------------------------------------
// Scan pass C (MFMA): ret = [C|S]@PPpre + tri(G)@V, scale, in-place over Vb.
// RT slab overlays the dead VT region (barrier separates).
// ---------------------------------------------------------------------------
__global__ __launch_bounds__(256) void scanC(__hip_bfloat16* Vb,
                                             const ushort_t* __restrict__ CSg,
                                             const ushort_t* __restrict__ PPg,
                                             float* __restrict__ StatsG)
{
    __shared__ __align__(16) ushort_t VT[256 * 64];   // [d][64] swizzled; RT overlay
    __shared__ __align__(16) ushort_t PPT[256 * 64];  // [d][kk], swizzled octets
    __shared__ __align__(16) ushort_t CS[32 * 64];    // [l][c|s], swizzled octets
    __shared__ __align__(16) ushort_t G[32 * 40];     // [l][l'], pad->40
    __shared__ float2 statsL[4][32];

    const int t = threadIdx.x;
    const int bch = blockIdx.x, dh = blockIdx.y;
    const int b = bch >> 6, ch = bch & 63;
    const size_t vbase = ((size_t)b * LL + ch * 32) * DD + dh * 256;

    {   // stage PPT + CS via async direct-to-LDS (pre-swizzled in global)
        const ushort_t* ppg = PPg + ((size_t)bch * 512 + dh * 256) * 64;
        #pragma unroll
        for (int i = 0; i < 8; ++i)
            gl_lds16(ppg + (size_t)(i * 256 + t) * 8,
                     (char*)PPT + (size_t)(i * 256 + t) * 16);
        const ushort_t* csg = CSg + ((size_t)b * NCH + ch) * 2048;
        gl_lds16(csg + (size_t)t * 8, (char*)CS + (size_t)t * 16);
    }
    {   // stage V^T (swizzled-octet rows)
        const int lg = t >> 5, dg = t & 31;
        ushort8 r[4];
        #pragma unroll
        for (int i = 0; i < 4; ++i)
            r[i] = *(const ushort8*)((const ushort_t*)Vb + vbase
                                     + (size_t)(lg * 4 + i) * DD + dg * 8);
        const int oct = (lg >> 1) ^ (dg & 7);
        const int sub = (lg & 1) * 4;
        #pragma unroll
        for (int jd = 0; jd < 8; ++jd) {
            ushort4 w4 = {r[0][jd], r[1][jd], r[2][jd], r[3][jd]};
            *(ushort4*)&VT[(dg * 8 + jd) * 64 + oct * 8 + sub] = w4;
        }
    }
    __syncthreads();

    const int w = t >> 6, l = t & 63, l15 = l & 15, hi = l >> 4;

    // load C/S fragments once (swizzled-octet reads)
    bf16x8 fc[2], fs[2];
    #pragma unroll
    for (int mt = 0; mt < 2; ++mt) {
        const int row = l15 + 16 * mt;
        fc[mt] = *(const bf16x8*)&CS[row * 64 + ((hi ^ (row & 7)) << 3)];
        fs[mt] = *(const bf16x8*)&CS[row * 64 + (((4 + hi) ^ (row & 7)) << 3)];
    }

    {   // G = tri(C@C^T + S@S^T)
        f32x4 gacc[2][2];
        #pragma unroll
        for (int mt = 0; mt < 2; ++mt)
            #pragma unroll
            for (int nt = 0; nt < 2; ++nt) {
                gacc[mt][nt] = f32x4{0.f,0.f,0.f,0.f};
                gacc[mt][nt] = __builtin_amdgcn_mfma_f32_16x16x32_bf16(fc[mt], fc[nt], gacc[mt][nt], 0,0,0);
                gacc[mt][nt] = __builtin_amdgcn_mfma_f32_16x16x32_bf16(fs[mt], fs[nt], gacc[mt][nt], 0,0,0);
            }
        #pragma unroll
        for (int mt = 0; mt < 2; ++mt)
            #pragma unroll
            for (int nt = 0; nt < 2; ++nt)
                #pragma unroll
                for (int r = 0; r < 4; ++r) {
                    const int row = 16 * mt + hi * 4 + r;
                    const int col = 16 * nt + l15;
                    float gv = (col <= row) ? gacc[mt][nt][r] : 0.f;
                    G[row * 40 + col] = f2b(gv);
                }
    }

    bf16x8 ag[2];
    #pragma unroll
    for (int mt = 0; mt < 2; ++mt)
        ag[mt] = *(const bf16x8*)&G[(l15 + 16 * mt) * 40 + hi * 8];

    f32x4 acc[2][4];
    #pragma unroll
    for (int mt = 0; mt < 2; ++mt)
        #pragma unroll
        for (int nt = 0; nt < 4; ++nt)
            acc[mt][nt] = f32x4{0.f,0.f,0.f,0.f};
    #pragma unroll
    for (int nt = 0; nt < 4; ++nt) {
        const int drow = w * 64 + nt * 16 + l15;
        bf16x8 bp0 = *(const bf16x8*)((const char*)PPT + drow * 128 + ((hi ^ (drow & 7)) << 4));
        bf16x8 bp1 = *(const bf16x8*)((const char*)PPT + drow * 128 + (((4 + hi) ^ (drow & 7)) << 4));
        bf16x8 bv  = *(const bf16x8*)&VT[drow * 64 + ((hi ^ ((drow >> 3) & 7)) << 3)];
        #pragma unroll
        for (int mt = 0; mt < 2; ++mt) {
            acc[mt][nt] = __builtin_amdgcn_mfma_f32_16x16x32_bf16(fc[mt], bp0, acc[mt][nt], 0,0,0);
            acc[mt][nt] = __builtin_amdgcn_mfma_f32_16x16x32_bf16(fs[mt], bp1, acc[mt][nt], 0,0,0);
            acc[mt][nt] = __builtin_amdgcn_mfma_f32_16x16x32_bf16(ag[mt], bv,  acc[mt][nt], 0,0,0);
        }
    }

    __syncthreads();   // VT reads complete in all waves; RT overlays VT region
    ushort_t* RTw = VT + w * 2048;     // per-wave [32][64] slab

    float sP[2][4] = {}, qP[2][4] = {};
    #pragma unroll
    for (int mt = 0; mt < 2; ++mt)
        #pragma unroll
        for (int nt = 0; nt < 4; ++nt)
            #pragma unroll
            for (int r = 0; r < 4; ++r) {
                const int lrow = 16 * mt + hi * 4 + r;
                const float scale = rsqrtf((float)((ch * 32 + lrow + 1) * KK));
                const float val = acc[mt][nt][r] * scale;
                sP[mt][r] += val;
                qP[mt][r] = fmaf(val, val, qP[mt][r]);
                RTw[lrow * 64 + nt * 16 + l15] = f2b(val);
            }
    #pragma unroll
    for (int c = 0; c < 4; ++c) {
        const int cid = c * 64 + l;
        const int row = cid >> 3, c8 = cid & 7;
        ushort8 v = *(const ushort8*)&RTw[row * 64 + c8 * 8];
        *(ushort8*)((ushort_t*)Vb + ((size_t)b * LL + ch * 32 + row) * DD
                    + dh * 256 + w * 64 + c8 * 8) = v;
    }
    #pragma unroll
    for (int mt = 0; mt < 2; ++mt)
        #pragma unroll
        for (int r = 0; r < 4; ++r) {
            float sv = sP[mt][r], qv = qP[mt][r];
            #pragma unroll
            for (int off = 1; off < 16; off <<= 1) {
                sv += __shfl_xor(sv, off);
                qv += __shfl_xor(qv, off);
            }
            if (l15 == 0)
                statsL[w][16 * mt + hi * 4 + r] = float2{sv, qv};
        }
    __syncthreads();
    if (t < 32) {
        float s = 0.f, q = 0.f;
        #pragma unroll
        for (int w4 = 0; w4 < 4; ++w4) {
            float2 p = statsL[w4][t];
            s += p.x; q += p.y;
        }
        const size_t rowg = (size_t)b * LL + ch * 32 + t;
        *(float2*)&StatsG[(rowg * 2 + dh) * 2] = float2{s, q};
    }
}

// ---------------------------------------------------------------------------
extern "C" void kernel_launch(void* const* d_in, const int* in_sizes, int n_in,
                              void* d_out, int out_size, void* d_ws, size_t ws_size,
                              hipStream_t stream)
{
    const float* x   = (const float*)d_in[0];
    const float* W1  = (const float*)d_in[1];
    const float* b1  = (const float*)d_in[2];
    const float* W2  = (const float*)d_in[3];
    const float* b2  = (const float*)d_in[4];
    const float* ps  = (const float*)d_in[5];
    const float* cs  = (const float*)d_in[6];
    const float* Wv  = (const float*)d_in[7];
    const float* bv  = (const float*)d_in[8];
    const float* lng = (const float*)d_in[9];
    const float* lnb = (const float*)d_in[10];
    const float* Wo  = (const float*)d_in[11];
    const float* bo  = (const float*)d_in[12];
    float* out = (float*)d_out;

    char* wsb = (char*)d_ws;
    __hip_bfloat16* Vb  = (__hip_bfloat16*)(wsb);                     // 4 MB
    ushort_t* PPg = (ushort_t*)(wsb + (4u << 20));                    // 8 MB
    ushort_t* CSg = (ushort_t*)(wsb + (12u << 20));                   // 512 KB
    __hip_bfloat16* xb  = (__hip_bfloat16*)(wsb + (13u << 20));       // 4 MB
    __hip_bfloat16* Hb  = (__hip_bfloat16*)(wsb + (17u << 20));       // 4 MB
    __hip_bfloat16* Wct = (__hip_bfloat16*)(wsb + (21u << 20));       // 1 MB
    __hip_bfloat16* Wot = (__hip_bfloat16*)(wsb + (22u << 20));       // 0.5 MB
    float* StatsG = (float*)(wsb + (23u << 20));                      // 64 KB
    float* Upart  = (float*)(wsb + (23u << 20) + (64u << 10));        // 32 KB
    float* Vpart  = (float*)(wsb + (23u << 20) + (96u << 10));        // 32 KB
    __hip_bfloat16* W2T = (__hip_bfloat16*)(wsb + (23u << 20) + (128u << 10)); // 32 KB

    prep<<<dim3(16, 16, 6), dim3(32, 8), 0, stream>>>(
        W1, Wv, Wo, W2, x, lng, lnb, bo, Wct, Wot, W2T, xb, Upart, Vpart);
    gemm_mfma<64, 0><<<dim3(8, 64), dim3(256), 0, stream>>>(
        (const ushort_t*)xb, (const ushort_t*)Wct, b1, bv, nullptr, Hb, Vb, nullptr, nullptr);
    scanA<<<dim3(BB * NCH, 2), dim3(256), 0, stream>>>(
        Vb, Hb, W2T, b2, ps, cs, CSg, PPg);
    scan_prefix<<<dim3(256), dim3(256), 0, stream>>>(PPg);
    scanC<<<dim3(BB * NCH, 2), dim3(256), 0, stream>>>(Vb, CSg, PPg, StatsG);
    gemm_mfma<32, 1><<<dim3(4, 128), dim3(256), 0, stream>>>(
        (const ushort_t*)Vb, (const ushort_t*)Wot, Upart, Vpart, x, nullptr, nullptr, out, StatsG);
}